// Round 1
// baseline (660.169 us; speedup 1.0000x reference)
//
#include <hip/hip_runtime.h>

namespace {

constexpr int H  = 16;
constexpr int NS = 256;   // H*H joint states
constexpr int T  = 512;
constexpr int D  = 64;
constexpr float SHIFT = 96.0f;   // log2-domain shift to keep linear alpha in fp32 range
constexpr float LN2 = 0.69314718055994530942f;

__global__ __launch_bounds__(256, 4) void fhmm_fwd(
    const float* __restrict__ seq,     // [B, T, D]
    const int*   __restrict__ lengths, // [B]
    const float* __restrict__ pw,      // [H, H]
    const float* __restrict__ px,      // [H, H]
    const float* __restrict__ py,      // [H, H, D]
    float*       __restrict__ out)     // [B]
{
  const int b  = blockIdx.x;
  const int s  = threadIdx.x;   // joint state = w*16 + x
  const int wq = s >> 4;        // this thread's w'
  const int xq = s & 15;        // this thread's x'

  __shared__ float a_lds[NS];
  __shared__ float aw_lds[NS];
  __shared__ float red[4];

  // Per-thread emission parameters in log2 domain:
  // emit_l2(y) = base2 + sum_d y[d]*dif[d]
  float dif[D];
  float base2;
  {
    float acc0 = 0.0f;
    const float* p = py + s * D;
#pragma unroll
    for (int d = 0; d < D; ++d) {
      float v   = p[d];
      float l1m = __log2f(1.0f - v);
      dif[d]    = __log2f(v) - l1m;
      acc0     += l1m;
    }
    base2 = acc0;
  }

  // Transition columns this thread needs:
  // aw[w',x] = sum_w alpha[w,x]*pw[w,w']   -> pwc[w] = pw[w][w']
  // an[w',x'] = sum_x aw[w',x]*px[x,x']    -> pxc[x] = px[x][x']
  float pwc[H], pxc[H];
#pragma unroll
  for (int k = 0; k < H; ++k) {
    pwc[k] = pw[k * H + wq];
    pxc[k] = px[k * H + xq];
  }

  const int len = lengths[b];
  const float* yb = seq + (size_t)b * (T * D);

  // ---- t = 0 : alpha0 = pw[0][w'] * px[0][x'] * exp2(emit_l2 + SHIFT)
  float e = base2 + SHIFT;
#pragma unroll
  for (int d = 0; d < D; ++d) e = fmaf(yb[d], dif[d], e);
  float tm = pw[wq] * px[xq] * exp2f(e);

  float acc;   // running log2-likelihood
  float alph;  // normalized alpha for this thread's state
  {
    float v = tm;
#pragma unroll
    for (int off = 32; off >= 1; off >>= 1) v += __shfl_xor(v, off, 64);
    if ((s & 63) == 0) red[s >> 6] = v;
    __syncthreads();
    float norm = red[0] + red[1] + red[2] + red[3];
    alph = tm * __builtin_amdgcn_rcpf(norm);
    acc  = __log2f(norm) - SHIFT;
  }

  // ---- t = 1 .. len-1 (steps t >= len carry alpha unchanged == stop early)
  for (int t = 1; t < len; ++t) {
    // Emission dot-product: y is block-uniform -> scalar loads + v_fmac(s,v)
    const float* y = yb + t * D;
    float e2 = base2 + SHIFT;
#pragma unroll
    for (int d = 0; d < D; ++d) e2 = fmaf(y[d], dif[d], e2);

    __syncthreads();              // WAR: prev-iter red/a_lds reads done
    a_lds[s] = alph;
    __syncthreads();
    float aw = 0.0f;
#pragma unroll
    for (int k = 0; k < H; ++k) aw = fmaf(pwc[k], a_lds[k * H + xq], aw);
    aw_lds[s] = aw;
    __syncthreads();
    float an = 0.0f;
#pragma unroll
    for (int k = 0; k < H; ++k) an = fmaf(pxc[k], aw_lds[wq * H + k], an);

    float tmv = an * exp2f(e2);

    float v = tmv;
#pragma unroll
    for (int off = 32; off >= 1; off >>= 1) v += __shfl_xor(v, off, 64);
    if ((s & 63) == 0) red[s >> 6] = v;
    __syncthreads();
    float norm = red[0] + red[1] + red[2] + red[3];
    alph = tmv * __builtin_amdgcn_rcpf(norm);
    acc += __log2f(norm) - SHIFT;
  }

  if (s == 0) out[b] = acc * LN2;
}

} // namespace

extern "C" void kernel_launch(void* const* d_in, const int* in_sizes, int n_in,
                              void* d_out, int out_size, void* d_ws, size_t ws_size,
                              hipStream_t stream) {
  const float* seq     = (const float*)d_in[0];
  const int*   lengths = (const int*)d_in[1];
  const float* pw      = (const float*)d_in[2];
  const float* px      = (const float*)d_in[3];
  const float* py      = (const float*)d_in[4];
  float*       out     = (float*)d_out;

  hipLaunchKernelGGL(fhmm_fwd, dim3(1024), dim3(256), 0, stream,
                     seq, lengths, pw, px, py, out);
}